// Round 2
// baseline (704.636 us; speedup 1.0000x reference)
//
#include <hip/hip_runtime.h>
#include <stdint.h>

// ---------------------------------------------------------------------------
// TreeLayer: h = x @ M + x_init, M = tw^2*blockdiag + bbw*strict_block_upper,
// then per-column ActNorm + sigmoid.
// R3: revert to the proven 128x128 / 4-wave R1 GEMM body; add the T3-minimum
// pipeline: double-buffered LDS (2x32KB), stage(t+1) issued BEFORE compute(t),
// single raw s_barrier + vmcnt(0) per K-step (replaces 2x __syncthreads full
// drain). Paired-jc jobs: block b does jc=31-p then jc=p -> uniform weight 33,
// grid 1024. prep = fused x->bf16 convert + M^T build (from R2).
// ---------------------------------------------------------------------------

#define BATCH 8192
#define DIM   4096

typedef __bf16 v8bf __attribute__((ext_vector_type(8)));
typedef float  v4f  __attribute__((ext_vector_type(4)));

__device__ __forceinline__ unsigned short f2bf(float f) {
  unsigned int u = __float_as_uint(f);
  u += 0x7fffu + ((u >> 16) & 1u);          // round-to-nearest-even
  return (unsigned short)(u >> 16);
}
__device__ __forceinline__ float bf2f(unsigned int h16) {
  return __uint_as_float(h16 << 16);
}

__device__ __forceinline__ void async_copy16(const void* g, void* l) {
  __builtin_amdgcn_global_load_lds(
      (__attribute__((address_space(1))) void*)g,
      (__attribute__((address_space(3))) void*)l, 16, 0, 0);
}

// ------------------- fused: x (fp32)->bf16  +  build M^T -------------------
// blocks [0, 16384): convert x; blocks [16384, 20480): build Mt 64x64 tiles.
__global__ __launch_bounds__(256) void prep(
    const float4* __restrict__ x, uint4* __restrict__ Xb,
    const float* __restrict__ tw, const float* __restrict__ bbw,
    unsigned short* __restrict__ Mt) {
  const int b = (int)blockIdx.x;
  const int t = (int)threadIdx.x;
  __shared__ float tile[64 * 65];
  if (b < 16384) {
    int i = b * 256 + t;
    float4 a = x[2 * i], c = x[2 * i + 1];
    uint4 o;
    o.x = (unsigned)f2bf(a.x) | ((unsigned)f2bf(a.y) << 16);
    o.y = (unsigned)f2bf(a.z) | ((unsigned)f2bf(a.w) << 16);
    o.z = (unsigned)f2bf(c.x) | ((unsigned)f2bf(c.y) << 16);
    o.w = (unsigned)f2bf(c.z) | ((unsigned)f2bf(c.w) << 16);
    Xb[i] = o;
  } else {
    const int bb = b - 16384;
    const int kt = bb & 63, nt = bb >> 6;
    const int jj = t & 63, i0 = t >> 6;
    if (kt <= nt) {
      const bool diag = (kt == nt);
      const float* S = diag ? tw : bbw;
      #pragma unroll
      for (int r = 0; r < 16; ++r) {
        int i = i0 + r * 4;                                   // k-local
        float v = S[(size_t)(kt * 64 + i) * DIM + nt * 64 + jj];
        tile[i * 65 + jj] = diag ? v * v : v;
      }
      __syncthreads();
      #pragma unroll
      for (int r = 0; r < 16; ++r) {
        int nl = i0 + r * 4;                                  // n-local
        Mt[(size_t)(nt * 64 + nl) * DIM + kt * 64 + jj] = f2bf(tile[jj * 65 + nl]);
      }
    } else {
      #pragma unroll
      for (int r = 0; r < 16; ++r) {
        int nl = i0 + r * 4;
        Mt[(size_t)(nt * 64 + nl) * DIM + kt * 64 + jj] = 0;
      }
    }
  }
}

// --------------------------- main GEMM + epilogue --------------------------
// C[8192,4096] = Xb @ M  (M block-upper-tri => K loop only to (jc+1)*128)
// 128x128 tile, BK=64, 4 waves (2x2), each wave 64x64 via 4x4 mfma 16x16x32.
// LDS XOR-swizzle: within each 128B row, 16B chunk c stored at c ^ (row & 7);
// staging pre-swizzles the GLOBAL source chunk (linear LDS dest preserves
// global_load_lds's lane*16B scatter); fragment reads then conflict-free.
// Pipeline (T3-minimum): per K-step t, issue the 8 global_load_lds for t+1
// into buf^1 FIRST, then ds_read+MFMA from buf, then s_waitcnt vmcnt(0) +
// one raw s_barrier. Staging flies under the 32 MFMAs; no full-drain
// __syncthreads in the loop.
__global__ __launch_bounds__(256) void gemm_tree(
    const unsigned short* __restrict__ Xb,    // [8192][4096] bf16
    const unsigned short* __restrict__ Mt,    // [4096 n][4096 k] bf16 (M^T)
    const float* __restrict__ Xi,             // x_init fp32
    unsigned short* __restrict__ H,           // h out, bf16
    float* __restrict__ colsum,
    float* __restrict__ colsumsq) {
  __shared__ unsigned short As[2 * 8192];     // 2 x [128 rows][64 k] swizzled
  __shared__ unsigned short Bs[2 * 8192];     // 2 x [128 n   ][64 k] swizzled

  const int b = (int)blockIdx.x;              // 1024 blocks, weight-33 each
  const int p = b >> 6;                       // pairing group 0..15
  const int bm = b & 63;                      // M-tile
  const int tid = (int)threadIdx.x;
  const int wave = tid >> 6, lane = tid & 63;
  const int wm = (wave & 1) * 64, wn = (wave >> 1) * 64;
  const int lr = lane & 15, quad = lane >> 4;
  const int srow = lane >> 3;                 // row within 8-row segment
  const int scol = ((lane & 7) ^ srow) * 8;   // pre-swizzled source k-chunk

  for (int job = 0; job < 2; ++job) {
    const int jc = job ? p : 31 - p;          // heavy job first
    const int nsteps = (jc + 1) * 2;          // K-steps of 64
    const size_t arow0 = (size_t)bm * 128;
    const size_t brow0 = (size_t)jc * 128;

    v4f acc[4][4];
    #pragma unroll
    for (int mi = 0; mi < 4; ++mi)
      #pragma unroll
      for (int ni = 0; ni < 4; ++ni) acc[mi][ni] = {0.f, 0.f, 0.f, 0.f};

    // prologue: stage step 0 into buf 0
    #pragma unroll
    for (int r = 0; r < 4; ++r) {
      int seg = wave * 4 + r;                 // 16 segments x 1KB per matrix
      int row = seg * 8 + srow;
      async_copy16(Xb + (arow0 + row) * DIM + scol, &As[seg * 512]);
      async_copy16(Mt + (brow0 + row) * DIM + scol, &Bs[seg * 512]);
    }
    asm volatile("s_waitcnt vmcnt(0)" ::: "memory");
    __builtin_amdgcn_s_barrier();
    __builtin_amdgcn_sched_barrier(0);

    for (int t = 0; t < nsteps; ++t) {
      const int cur = (t & 1) * 8192;
      // issue next-step staging first: lands under this step's MFMAs
      if (t + 1 < nsteps) {
        const int nxt = ((t + 1) & 1) * 8192;
        const size_t nk = (size_t)(t + 1) * 64 + scol;
        #pragma unroll
        for (int r = 0; r < 4; ++r) {
          int seg = wave * 4 + r;
          int row = seg * 8 + srow;
          async_copy16(Xb + (arow0 + row) * DIM + nk, &As[nxt + seg * 512]);
          async_copy16(Mt + (brow0 + row) * DIM + nk, &Bs[nxt + seg * 512]);
        }
      }
      #pragma unroll
      for (int kk = 0; kk < 2; ++kk) {
        const int sw = ((kk * 4 + quad) ^ (lr & 7)) * 8;   // swizzled chunk
        v8bf a[4], bb[4];
        #pragma unroll
        for (int mi = 0; mi < 4; ++mi)
          a[mi] = *(const v8bf*)&As[cur + (wm + mi * 16 + lr) * 64 + sw];
        #pragma unroll
        for (int ni = 0; ni < 4; ++ni)
          bb[ni] = *(const v8bf*)&Bs[cur + (wn + ni * 16 + lr) * 64 + sw];
        #pragma unroll
        for (int mi = 0; mi < 4; ++mi)
          #pragma unroll
          for (int ni = 0; ni < 4; ++ni)
            acc[mi][ni] = __builtin_amdgcn_mfma_f32_16x16x32_bf16(
                a[mi], bb[ni], acc[mi][ni], 0, 0, 0);
      }
      asm volatile("s_waitcnt vmcnt(0)" ::: "memory");  // t+1 staged
      __builtin_amdgcn_s_barrier();                      // all waves done w/ buf
      __builtin_amdgcn_sched_barrier(0);
    }

    // Epilogue: h = acc + x_init; store bf16 h; per-column sum/sumsq atomics.
    // C/D layout: col = lane&15, row = quad*4 + reg  [m89/m91 verified]
    const int colT = jc * 128 + wn + lr;
    const int rowT = bm * 128 + wm + quad * 4;
    #pragma unroll
    for (int ni = 0; ni < 4; ++ni) {
      int col = colT + ni * 16;
      float s = 0.f, sq = 0.f;
      #pragma unroll
      for (int mi = 0; mi < 4; ++mi) {
        int row = rowT + mi * 16;
        #pragma unroll
        for (int r = 0; r < 4; ++r) {
          size_t idx = (size_t)(row + r) * DIM + col;
          float h = acc[mi][ni][r] + Xi[idx];
          H[idx] = f2bf(h);
          s += h;
          sq += h * h;
        }
      }
      // lanes l, l+16, l+32, l+48 hold the same column -> xor-reduce over quads
      s += __shfl_xor(s, 16);  s += __shfl_xor(s, 32);
      sq += __shfl_xor(sq, 16); sq += __shfl_xor(sq, 32);
      if (quad == 0) {
        atomicAdd(&colsum[col], s);
        atomicAdd(&colsumsq[col], sq);
      }
    }
  }
}

// ------------------------- column stats -> mean/scale ----------------------
__global__ __launch_bounds__(256) void finalize_stats(
    const float* __restrict__ colsum, const float* __restrict__ colsumsq,
    float* __restrict__ mean, float* __restrict__ scale) {
  int i = blockIdx.x * 256 + threadIdx.x;
  float m = colsum[i] * (1.0f / BATCH);
  float var = fmaxf(colsumsq[i] * (1.0f / BATCH) - m * m, 0.0f);
  mean[i] = m;
  scale[i] = 1.0f / (sqrtf(var) + 1e-6f);     // (h-mean)*tree_scale^2 = (h-mean)/(std+eps)
}

// ------------------------- normalize + sigmoid -----------------------------
__global__ __launch_bounds__(256) void norm_sigmoid(
    const uint4* __restrict__ H, const float* __restrict__ mean,
    const float* __restrict__ scale, float4* __restrict__ out) {
  int i = blockIdx.x * 256 + threadIdx.x;     // 8-elem group, row-major
  int cg = (i & 511) << 3;                    // column of first element
  uint4 h = H[i];
  float4 m0 = *(const float4*)&mean[cg],  m1 = *(const float4*)&mean[cg + 4];
  float4 s0 = *(const float4*)&scale[cg], s1 = *(const float4*)&scale[cg + 4];
  float hv[8];
  hv[0] = bf2f(h.x & 0xffffu); hv[1] = bf2f(h.x >> 16);
  hv[2] = bf2f(h.y & 0xffffu); hv[3] = bf2f(h.y >> 16);
  hv[4] = bf2f(h.z & 0xffffu); hv[5] = bf2f(h.z >> 16);
  hv[6] = bf2f(h.w & 0xffffu); hv[7] = bf2f(h.w >> 16);
  float mm[8] = {m0.x, m0.y, m0.z, m0.w, m1.x, m1.y, m1.z, m1.w};
  float ss[8] = {s0.x, s0.y, s0.z, s0.w, s1.x, s1.y, s1.z, s1.w};
  #pragma unroll
  for (int j = 0; j < 8; ++j) {
    float z = (hv[j] - mm[j]) * ss[j];
    hv[j] = 1.0f / (1.0f + __expf(-z));
  }
  out[2 * i]     = make_float4(hv[0], hv[1], hv[2], hv[3]);
  out[2 * i + 1] = make_float4(hv[4], hv[5], hv[6], hv[7]);
}

// ---------------------------------------------------------------------------
extern "C" void kernel_launch(void* const* d_in, const int* in_sizes, int n_in,
                              void* d_out, int out_size, void* d_ws, size_t ws_size,
                              hipStream_t stream) {
  const float* x      = (const float*)d_in[0];
  const float* x_init = (const float*)d_in[1];
  const float* tw     = (const float*)d_in[2];
  const float* bbw    = (const float*)d_in[3];
  float* out = (float*)d_out;

  char* ws = (char*)d_ws;
  // ws layout: Xb 64MB | Mt 32MB | H 64MB | colsum/colsumsq/mean/scale 4x16KB
  unsigned short* Xb = (unsigned short*)(ws);
  unsigned short* Mt = (unsigned short*)(ws + (size_t)67108864);
  unsigned short* H  = (unsigned short*)(ws + (size_t)100663296);
  float* colsum   = (float*)(ws + (size_t)167772160);
  float* colsumsq = (float*)(ws + (size_t)167772160 + 16384);
  float* mean     = (float*)(ws + (size_t)167772160 + 32768);
  float* scale    = (float*)(ws + (size_t)167772160 + 49152);

  // ws is re-poisoned to 0xAA before every timed launch -> zero accumulators.
  hipMemsetAsync(colsum, 0, 32768, stream);

  prep<<<20480, 256, 0, stream>>>((const float4*)x, (uint4*)Xb, tw, bbw, Mt);
  gemm_tree<<<1024, 256, 0, stream>>>(Xb, Mt, x_init, H, colsum, colsumsq);
  finalize_stats<<<16, 256, 0, stream>>>(colsum, colsumsq, mean, scale);
  norm_sigmoid<<<(BATCH * DIM / 8 + 255) / 256, 256, 0, stream>>>(
      (const uint4*)H, mean, scale, (float4*)out);
}